// Round 12
// baseline (4675.046 us; speedup 1.0000x reference)
//
#include <hip/hip_runtime.h>
#include <hip/hip_bf16.h>
#include <stdint.h>

// ---------------------------------------------------------------------------
// Transformer block, B=4 S=2048 E=2048 H=1.
// H=1 -> softmax over size-1 axis == 1.0 -> attn_out = x @ w_kv + b_kv.
// t1 = x + (x@w_kv + b_kv); h = LN1(t1); g = gelu(h@w_fc + b_fc);
// t2 = x + (g@w_mproj + b_mproj); out = LN2(t2).
//
// GEMM R12: cross-BLOCK overlap instead of intra-block scheduling. Seven
// schedule topologies (R3,R5,R6,R8,R9,R10,R11) all pinned at 6190 cyc/tile,
// 37% MfmaUtil with 1 block/CU (128KB LDS): every drain idles the whole CU.
// Now: SINGLE-buffer BK=64 -> 64KB LDS -> 2 blocks/CU (launch_bounds(512,4)).
// Per tile: reads (counted hints; RAW correctness carried by compiler's own
// waits) -> q00,q01 -> re-read A1 -> hard lgk0 + barrier (buffer free) ->
// stage tile t+1 -> q10,q11 under the DMA -> vmcnt(0) drain -> barrier.
// The exposed drain of one block is filled by the co-resident block.
// Also: 2D-chunked XCD mapping (4bm x 8bn tiles/XCD) to cut the 8.5x
// A/B re-fetch (FETCH 541MB vs 64MB unique).
// Staging/fragment addressing bit-identical to R8/R11 (absmax 0.031 proven).
// ---------------------------------------------------------------------------

typedef __attribute__((ext_vector_type(4))) float f32x4;
typedef __attribute__((ext_vector_type(8))) __bf16 bf16x8;
typedef __attribute__((ext_vector_type(8))) unsigned short ushort8;

__device__ __forceinline__ unsigned short f2bf(float f) {
  unsigned int u = __float_as_uint(f);
  return (unsigned short)((u + 0x7FFFu + ((u >> 16) & 1u)) >> 16);  // RNE
}

__device__ __forceinline__ void gload_lds16(const void* g, void* l) {
  __builtin_amdgcn_global_load_lds(
      (const __attribute__((address_space(1))) unsigned int*)(uintptr_t)g,
      (__attribute__((address_space(3))) unsigned int*)(unsigned int)(uintptr_t)l,
      16, 0, 0);
}

// Bare counted hints (no clobber): compiler's own auto-waits carry RAW
// correctness; these only encourage earlier MFMA start.
#define HINT_LGK(n) asm volatile("s_waitcnt lgkmcnt(" #n ")")
// Hard-ordered (cross-wave race points only).
#define WAITLGK0_HARD() asm volatile("s_waitcnt lgkmcnt(0)" ::: "memory")
#define WAITVM0_HARD() asm volatile("s_waitcnt vmcnt(0)" ::: "memory")
#define SBAR() __builtin_amdgcn_s_barrier()

// ---------------------------------------------------------------------------
// f32 -> bf16 convert
// ---------------------------------------------------------------------------
__global__ __launch_bounds__(256) void cvt_bf16_kernel(
    const float* __restrict__ in, unsigned short* __restrict__ out, int n8) {
  int i = blockIdx.x * 256 + threadIdx.x;
  if (i >= n8) return;
  const size_t base = (size_t)i * 8;
  float4 a = *(const float4*)(in + base);
  float4 b = *(const float4*)(in + base + 4);
  ushort8 o;
  o[0] = f2bf(a.x); o[1] = f2bf(a.y); o[2] = f2bf(a.z); o[3] = f2bf(a.w);
  o[4] = f2bf(b.x); o[5] = f2bf(b.y); o[6] = f2bf(b.z); o[7] = f2bf(b.w);
  *(ushort8*)(out + base) = o;
}

// ---------------------------------------------------------------------------
// Transpose + convert: W (R x C f32) -> WT (C x R bf16)
// ---------------------------------------------------------------------------
__global__ __launch_bounds__(256) void transpose_cvt(
    const float* __restrict__ W, unsigned short* __restrict__ WT, int R, int C) {
  __shared__ unsigned short t[64][66];
  const int c0 = blockIdx.x * 64, r0 = blockIdx.y * 64;
  const int tid = threadIdx.x;
  const int lr = tid >> 4;
  const int lc = (tid & 15) * 4;
#pragma unroll
  for (int p = 0; p < 4; ++p) {
    const int r = lr + p * 16;
    float4 v = *(const float4*)(W + (size_t)(r0 + r) * C + c0 + lc);
    t[r][lc + 0] = f2bf(v.x);
    t[r][lc + 1] = f2bf(v.y);
    t[r][lc + 2] = f2bf(v.z);
    t[r][lc + 3] = f2bf(v.w);
  }
  __syncthreads();
#pragma unroll
  for (int p = 0; p < 4; ++p) {
    const int oc = lr + p * 16;
    ushort4 o;
    o.x = t[lc + 0][oc];
    o.y = t[lc + 1][oc];
    o.z = t[lc + 2][oc];
    o.w = t[lc + 3][oc];
    *(ushort4*)(WT + (size_t)(c0 + oc) * R + r0 + lc) = o;
  }
}

// ---------------------------------------------------------------------------
// 256x256 bf16 GEMM, single-buffer BK=64, 2 blocks/CU.
// A: MxK, BT: NxK (bf16, rows%256==0, K%128==0).
// EPI 0: f32 = acc+bias+xres; EPI 1: bf16 gelu(acc+bias).
// ---------------------------------------------------------------------------
template <int EPI>
__global__ __launch_bounds__(512, 4) void gemm256(
    const unsigned short* __restrict__ A, const unsigned short* __restrict__ BT,
    const float* __restrict__ bias, const float* __restrict__ xres,
    void* __restrict__ out, int N, int K) {
  // L[op][region][128*64] ; 64 KiB total -> 2 blocks/CU.
  __shared__ unsigned short L[2][2][8192];

  const int tid = threadIdx.x;
  const int lane = tid & 63;
  const int w = tid >> 6;  // 0..7
  const int wm = w >> 2;   // 0..1 -> rows wm*128
  const int wn = w & 3;    // 0..3 -> cols wn*64
  const int l15 = lane & 15;

  // ---- XCD mapping: 4bm x 8bn 2D chunks per XCD (L2 locality) ----
  const int nbn = N / 256;
  const int nwg = gridDim.x;
  const int bid = blockIdx.x;
  const int xcd = bid & 7;
  const int Q = nwg >> 3;
  const int ii = bid >> 3;
  const int bmr = Q / nbn;  // bm rows per XCD
  int bm, bn;
  if (bmr > 0 && bmr * nbn == Q && (nbn & 7) == 0 && (Q & 7) == 0) {
    bm = xcd * bmr + ((ii >> 3) % bmr);
    bn = (ii & 7) + 8 * ((ii >> 3) / bmr);
  } else {  // fallback: contiguous strip per XCD
    const int wg = xcd * Q + ii;
    bm = wg / nbn;
    bn = wg % nbn;
  }

  const int nt = K / 64;

  // ---- staging lane addressing (identical to R6-R11, refcheck-proven) ----
  const int srow = w * 8 + (lane >> 3);
  const int schunk = (lane & 7) ^ ((lane >> 3) & 7);
  const unsigned short* pb[2][2][2];  // [op][h][j]
#pragma unroll
  for (int h = 0; h < 2; ++h)
#pragma unroll
    for (int j = 0; j < 2; ++j) {
      pb[0][h][j] =
          A + (size_t)(bm * 256 + j * 128 + h * 64 + srow) * K + schunk * 8;
      pb[1][h][j] = BT +
                    (size_t)(bn * 256 + ((srow >> 5) + 2 * j) * 64 + h * 32 +
                             (srow & 31)) * K +
                    schunk * 8;
    }

#define STAGE(OP, H, TILE)                                                 \
  {                                                                        \
    const size_t ko_ = (size_t)(TILE) * 64;                                \
    gload_lds16(pb[OP][H][0] + ko_, &L[OP][H][w * 512]);                   \
    gload_lds16(pb[OP][H][1] + ko_, &L[OP][H][w * 512 + 4096]);            \
  }

  // ---- fragment read addressing (identical to R6-R11) ----
  const int kq = lane >> 4;
  const int x7 = lane & 7;
  const int cc0 = ((kq ^ x7) << 4);
  const int cc1 = (((4 + kq) ^ x7) << 4);
  const int rAoff = (wm * 64 + l15) * 128;
  const int rBoff = (wn * 32 + l15) * 128;

  f32x4 acc[8][4] = {};
  bf16x8 aF[4][2], b0F[2][2], b1F[2][2];

#define RD_A(H)                                                        \
  {                                                                    \
    const char* p_ = (const char*)&L[0][H][0] + rAoff;                 \
    _Pragma("unroll") for (int mf = 0; mf < 4; ++mf) {                 \
      aF[mf][0] = *(const bf16x8*)(p_ + mf * 2048 + cc0);              \
      aF[mf][1] = *(const bf16x8*)(p_ + mf * 2048 + cc1);              \
    }                                                                  \
  }
#define RD_B(H, DST)                                                   \
  {                                                                    \
    const char* p_ = (const char*)&L[1][H][0] + rBoff;                 \
    _Pragma("unroll") for (int nf = 0; nf < 2; ++nf) {                 \
      DST[nf][0] = *(const bf16x8*)(p_ + nf * 2048 + cc0);             \
      DST[nf][1] = *(const bf16x8*)(p_ + nf * 2048 + cc1);             \
    }                                                                  \
  }
#define CLUSTER(BSET, MO, NO)                                               \
  __builtin_amdgcn_s_setprio(1);                                            \
  _Pragma("unroll") for (int mf = 0; mf < 4; ++mf)                          \
      _Pragma("unroll") for (int nf = 0; nf < 2; ++nf)                      \
          _Pragma("unroll") for (int ks = 0; ks < 2; ++ks)                  \
              acc[MO + mf][NO + nf] =                                       \
                  __builtin_amdgcn_mfma_f32_16x16x32_bf16(                  \
                      aF[mf][ks], BSET[nf][ks], acc[MO + mf][NO + nf],      \
                      0, 0, 0);                                             \
  __builtin_amdgcn_s_setprio(0);

  // ---- prologue: stage tile 0, drain, sync ----
  STAGE(1, 0, 0); STAGE(0, 0, 0); STAGE(1, 1, 0); STAGE(0, 1, 0);
  WAITVM0_HARD();
  SBAR();

  for (int t = 0; t < nt; ++t) {
    const int ts = (t + 1 < nt) ? t + 1 : nt - 1;  // clamp: dead on last iter
    // reads for the whole tile's first half + both B sets
    RD_A(0);
    RD_B(0, b0F);
    RD_B(1, b1F);
    HINT_LGK(4);
    CLUSTER(b0F, 0, 0);  // q00
    HINT_LGK(0);
    CLUSTER(b1F, 0, 2);  // q01
    RD_A(1);             // overwrite aF with A1
    WAITLGK0_HARD();     // all my reads retired (pins above barrier)
    SBAR();              // all waves' reads retired -> buffer free
    // stage tile t+1 into the (single) buffer; q10/q11 run under the DMA
    STAGE(1, 0, ts); STAGE(0, 0, ts); STAGE(1, 1, ts); STAGE(0, 1, ts);
    CLUSTER(b0F, 4, 0);  // q10 (reg-resident operands)
    CLUSTER(b1F, 4, 2);  // q11
    WAITVM0_HARD();      // tile t+1 landed (drain filled by co-resident block)
    SBAR();
  }

  // ---- epilogue: C/D layout col = lane&15, row = (lane>>4)*4 + reg ----
  const int col0 = bn * 256 + wn * 64 + l15;
  const int row0 = bm * 256 + wm * 128 + ((lane >> 4) << 2);
  float bv[4];
#pragma unroll
  for (int n = 0; n < 4; ++n) bv[n] = bias[col0 + n * 16];
#pragma unroll
  for (int mf = 0; mf < 8; ++mf) {
#pragma unroll
    for (int j = 0; j < 4; ++j) {
      const size_t row = (size_t)(row0 + mf * 16 + j);
#pragma unroll
      for (int n = 0; n < 4; ++n) {
        const size_t idx = row * N + col0 + n * 16;
        float v = acc[mf][n][j] + bv[n];
        if (EPI == 0) {
          ((float*)out)[idx] = v + xres[idx];
        } else {
          float ge = 0.5f * v * (1.0f + erff(v * 0.7071067811865475f));
          ((unsigned short*)out)[idx] = f2bf(ge);
        }
      }
    }
  }
#undef RD_A
#undef RD_B
#undef CLUSTER
#undef STAGE
}

// ---------------------------------------------------------------------------
// Row LayerNorm over E=2048: one block per row, 8 elems/thread.
// ---------------------------------------------------------------------------
template <int OUT_BF16>
__global__ __launch_bounds__(256) void ln_row(const float* __restrict__ tin,
                                              const float* __restrict__ gw,
                                              const float* __restrict__ bw,
                                              void* __restrict__ outp) {
  const int row = blockIdx.x;
  const int tid = threadIdx.x;
  const size_t base = (size_t)row * 2048 + tid * 8;
  alignas(16) float v[8];
  *(float4*)(v) = *(const float4*)(tin + base);
  *(float4*)(v + 4) = *(const float4*)(tin + base + 4);
  float s = 0.f, q = 0.f;
#pragma unroll
  for (int i = 0; i < 8; ++i) { s += v[i]; q += v[i] * v[i]; }
#pragma unroll
  for (int m = 32; m >= 1; m >>= 1) {
    s += __shfl_xor(s, m);
    q += __shfl_xor(q, m);
  }
  __shared__ float red[8];
  if ((tid & 63) == 0) {
    red[tid >> 6] = s;
    red[4 + (tid >> 6)] = q;
  }
  __syncthreads();
  s = red[0] + red[1] + red[2] + red[3];
  q = red[4] + red[5] + red[6] + red[7];
  const float mean = s * (1.0f / 2048.0f);
  float var = q * (1.0f / 2048.0f) - mean * mean;
  var = fmaxf(var, 0.0f);
  const float rstd = rsqrtf(var + 1e-5f);
  alignas(16) float gv[8], bv[8];
  *(float4*)(gv) = *(const float4*)(gw + (size_t)tid * 8);
  *(float4*)(gv + 4) = *(const float4*)(gw + (size_t)tid * 8 + 4);
  *(float4*)(bv) = *(const float4*)(bw + (size_t)tid * 8);
  *(float4*)(bv + 4) = *(const float4*)(bw + (size_t)tid * 8 + 4);
  if (OUT_BF16) {
    ushort8 o;
#pragma unroll
    for (int i = 0; i < 8; ++i)
      o[i] = f2bf((v[i] - mean) * rstd * gv[i] + bv[i]);
    *(ushort8*)((unsigned short*)outp + base) = o;
  } else {
    alignas(16) float r[8];
#pragma unroll
    for (int i = 0; i < 8; ++i) r[i] = (v[i] - mean) * rstd * gv[i] + bv[i];
    *(float4*)((float*)outp + base) = *(float4*)(r);
    *(float4*)((float*)outp + base + 4) = *(float4*)(r + 4);
  }
}

// ---------------------------------------------------------------------------
// Launcher — workspace-size-adaptive (R2+ evidence: full path taken).
// ---------------------------------------------------------------------------
extern "C" void kernel_launch(void* const* d_in, const int* in_sizes, int n_in,
                              void* d_out, int out_size, void* d_ws,
                              size_t ws_size, hipStream_t stream) {
  constexpr int M = 8192;  // B*S
  constexpr int E = 2048;
  constexpr int F = 8192;  // 4*E
  const size_t MiB = 1ull << 20;

  const float* x = (const float*)d_in[0];
  // d_in[1] mask, d_in[2] w_attn, d_in[3] b_attn: dead (softmax over size-1)
  const float* w_kv = (const float*)d_in[4];
  const float* b_kv = (const float*)d_in[5];
  const float* ln1_g = (const float*)d_in[6];
  const float* ln1_b = (const float*)d_in[7];
  const float* w_fc = (const float*)d_in[8];
  const float* b_fc = (const float*)d_in[9];
  const float* w_mproj = (const float*)d_in[10];
  const float* b_mproj = (const float*)d_in[11];
  const float* ln2_g = (const float*)d_in[12];
  const float* ln2_b = (const float*)d_in[13];
  float* out = (float*)d_out;
  char* ws = (char*)d_ws;

  float* tbuf = out;  // t1/t2 live in d_out; in-place LN is safe

  int nch;
  unsigned short *xb, *wkvT, *wfcT, *wmpT, *hb, *gch;
  if (ws_size >= 224 * MiB) {
    nch = 1;
    gch = (unsigned short*)(ws + 0);  // 128Mi; aliases xb+wkvT (dead by then)
    xb = (unsigned short*)(ws + 0);
    wkvT = (unsigned short*)(ws + 32 * MiB);
    wfcT = (unsigned short*)(ws + 128 * MiB);
    wmpT = (unsigned short*)(ws + 160 * MiB);
    hb = (unsigned short*)(ws + 192 * MiB);
  } else if (ws_size >= 160 * MiB) {
    nch = 2;
    gch = (unsigned short*)(ws + 0);
    xb = (unsigned short*)(ws + 0);
    wkvT = (unsigned short*)(ws + 32 * MiB);
    hb = (unsigned short*)(ws + 64 * MiB);
    wfcT = (unsigned short*)(ws + 96 * MiB);
    wmpT = (unsigned short*)(ws + 128 * MiB);
  } else {
    nch = 4;
    gch = (unsigned short*)(ws + 0);
    xb = (unsigned short*)(ws + 0);
    wkvT = (unsigned short*)(ws + 32 * MiB);
    hb = (unsigned short*)(ws + 32 * MiB);
    wfcT = (unsigned short*)(ws + 64 * MiB);
    wmpT = (unsigned short*)(ws + 96 * MiB);
  }

  cvt_bf16_kernel<<<(M * E / 8 + 255) / 256, 256, 0, stream>>>(x, xb, M * E / 8);
  transpose_cvt<<<dim3(E / 64, E / 64), 256, 0, stream>>>(w_kv, wkvT, E, E);
  transpose_cvt<<<dim3(F / 64, E / 64), 256, 0, stream>>>(w_fc, wfcT, E, F);
  transpose_cvt<<<dim3(E / 64, F / 64), 256, 0, stream>>>(w_mproj, wmpT, F, E);

  // t1 = x @ w_kv + b_kv + x
  gemm256<0><<<(M / 256) * (E / 256), 512, 0, stream>>>(xb, wkvT, b_kv, x,
                                                        tbuf, E, E);
  // h = LN1(t1) -> bf16
  ln_row<1><<<M, 256, 0, stream>>>(tbuf, ln1_g, ln1_b, hb);
  // g = gelu(h @ w_fc + b_fc); t2 = x + g @ w_mproj + b_mproj  (M-chunked)
  const int Mc = M / nch;
  for (int c = 0; c < nch; ++c) {
    const size_t roff = (size_t)c * Mc;
    gemm256<1><<<(Mc / 256) * (F / 256), 512, 0, stream>>>(
        hb + roff * E, wfcT, b_fc, nullptr, gch, F, E);
    gemm256<0><<<(Mc / 256) * (E / 256), 512, 0, stream>>>(
        gch, wmpT, b_mproj, x + roff * E, tbuf + roff * E, E, F);
  }
  // out = LN2(t2) in place
  ln_row<0><<<M, 256, 0, stream>>>(tbuf, ln2_g, ln2_b, out);
}

// Round 13
// 754.508 us; speedup vs baseline: 6.1961x; 6.1961x over previous
//
#include <hip/hip_runtime.h>
#include <hip/hip_bf16.h>
#include <stdint.h>

// ---------------------------------------------------------------------------
// Transformer block, B=4 S=2048 E=2048 H=1.
// H=1 -> softmax over size-1 axis == 1.0 -> attn_out = x @ w_kv + b_kv.
// t1 = x + (x@w_kv + b_kv); h = LN1(t1); g = gelu(h@w_fc + b_fc);
// t2 = x + (g@w_mproj + b_mproj); out = LN2(t2).
//
// GEMM R13 = R6's 8-phase kernel (best measured: 686.8us total) with the
// MFMA shape swapped 16x16x32 -> 32x32x16 (ubench 2075->2382 TF, half the
// MFMA instruction count: 32x8cyc vs 64x4.85cyc per wave-tile). Swap is
// isomorphic: same regions, same read counts/phase {12,4,8,0}, same chunk
// swizzle (read-chunk ks*2+(lane>>5), row&7==lane&7), same register budget.
// New lane maps: A/B row|col = lane&31, kgrp = lane>>5 (8 contiguous K);
// C/D col=lane&31, row=(reg&3)+8*(reg>>2)+4*(lane>>5) (m74/m101-verified).
// R12 post-mortem: launch_bounds(512,4) capped VGPR at 128 -> acc spilled
// (WRITE 5GB); 2 blocks/CU is arithmetically impossible at 256^2. Reverted.
// ---------------------------------------------------------------------------

typedef __attribute__((ext_vector_type(16))) float f32x16;
typedef __attribute__((ext_vector_type(8))) __bf16 bf16x8;
typedef __attribute__((ext_vector_type(8))) unsigned short ushort8;

__device__ __forceinline__ unsigned short f2bf(float f) {
  unsigned int u = __float_as_uint(f);
  return (unsigned short)((u + 0x7FFFu + ((u >> 16) & 1u)) >> 16);  // RNE
}

__device__ __forceinline__ void gload_lds16(const void* g, void* l) {
  __builtin_amdgcn_global_load_lds(
      (const __attribute__((address_space(1))) unsigned int*)(uintptr_t)g,
      (__attribute__((address_space(3))) unsigned int*)(unsigned int)(uintptr_t)l,
      16, 0, 0);
}

#define WAITLGK(n) asm volatile("s_waitcnt lgkmcnt(" #n ")" ::: "memory")
#define WAITVM(n) asm volatile("s_waitcnt vmcnt(" #n ")" ::: "memory")
#define SBAR() __builtin_amdgcn_s_barrier()

// ---------------------------------------------------------------------------
// f32 -> bf16 convert
// ---------------------------------------------------------------------------
__global__ __launch_bounds__(256) void cvt_bf16_kernel(
    const float* __restrict__ in, unsigned short* __restrict__ out, int n8) {
  int i = blockIdx.x * 256 + threadIdx.x;
  if (i >= n8) return;
  const size_t base = (size_t)i * 8;
  float4 a = *(const float4*)(in + base);
  float4 b = *(const float4*)(in + base + 4);
  ushort8 o;
  o[0] = f2bf(a.x); o[1] = f2bf(a.y); o[2] = f2bf(a.z); o[3] = f2bf(a.w);
  o[4] = f2bf(b.x); o[5] = f2bf(b.y); o[6] = f2bf(b.z); o[7] = f2bf(b.w);
  *(ushort8*)(out + base) = o;
}

// ---------------------------------------------------------------------------
// Transpose + convert: W (R x C f32) -> WT (C x R bf16)
// ---------------------------------------------------------------------------
__global__ __launch_bounds__(256) void transpose_cvt(
    const float* __restrict__ W, unsigned short* __restrict__ WT, int R, int C) {
  __shared__ unsigned short t[64][66];
  const int c0 = blockIdx.x * 64, r0 = blockIdx.y * 64;
  const int tid = threadIdx.x;
  const int lr = tid >> 4;
  const int lc = (tid & 15) * 4;
#pragma unroll
  for (int p = 0; p < 4; ++p) {
    const int r = lr + p * 16;
    float4 v = *(const float4*)(W + (size_t)(r0 + r) * C + c0 + lc);
    t[r][lc + 0] = f2bf(v.x);
    t[r][lc + 1] = f2bf(v.y);
    t[r][lc + 2] = f2bf(v.z);
    t[r][lc + 3] = f2bf(v.w);
  }
  __syncthreads();
#pragma unroll
  for (int p = 0; p < 4; ++p) {
    const int oc = lr + p * 16;
    ushort4 o;
    o.x = t[lc + 0][oc];
    o.y = t[lc + 1][oc];
    o.z = t[lc + 2][oc];
    o.w = t[lc + 3][oc];
    *(ushort4*)(WT + (size_t)(c0 + oc) * R + r0 + lc) = o;
  }
}

// ---------------------------------------------------------------------------
// 256x256 8-phase bf16 GEMM (R6 schedule, 32x32x16 MFMA).
// A: MxK, BT: NxK (bf16, rows%256==0, K%128==0).
// EPI 0: f32 = acc+bias+xres; EPI 1: bf16 gelu(acc+bias).
// ---------------------------------------------------------------------------
template <int EPI>
__global__ __launch_bounds__(512, 2) void gemm256(
    const unsigned short* __restrict__ A, const unsigned short* __restrict__ BT,
    const float* __restrict__ bias, const float* __restrict__ xres,
    void* __restrict__ out, int N, int K) {
  // L[buf][op][region][128*64] ; each region 16 KiB; total 128 KiB.
  __shared__ unsigned short L[2][2][2][8192];

  const int tid = threadIdx.x;
  const int lane = tid & 63;
  const int w = tid >> 6;  // 0..7
  const int wm = w >> 2;   // 0..1 -> rows wm*128
  const int wn = w & 3;    // 0..3 -> cols wn*64
  const int l31 = lane & 31;

  const int nbn = N / 256;
  const int nwg = gridDim.x;
  const int bid = blockIdx.x;
  const int wg = (bid & 7) * (nwg >> 3) + (bid >> 3);  // XCD-bijective (nwg%8==0)
  const int bm = wg / nbn, bn = wg % nbn;

  const int nt = K / 64;  // even

  // ---- staging lane addressing (identical to R6-R11, refcheck-proven) ----
  const int srow = w * 8 + (lane >> 3);
  const int schunk = (lane & 7) ^ ((lane >> 3) & 7);
  const unsigned short* pb[2][2][2];  // [op][h][j]
#pragma unroll
  for (int h = 0; h < 2; ++h)
#pragma unroll
    for (int j = 0; j < 2; ++j) {
      pb[0][h][j] =
          A + (size_t)(bm * 256 + j * 128 + h * 64 + srow) * K + schunk * 8;
      pb[1][h][j] = BT +
                    (size_t)(bn * 256 + ((srow >> 5) + 2 * j) * 64 + h * 32 +
                             (srow & 31)) * K +
                    schunk * 8;
    }

#define STAGE(BUF, OP, H, TILE)                                            \
  {                                                                        \
    const size_t ko_ = (size_t)(TILE) * 64;                                \
    gload_lds16(pb[OP][H][0] + ko_, &L[BUF][OP][H][w * 512]);              \
    gload_lds16(pb[OP][H][1] + ko_, &L[BUF][OP][H][w * 512 + 4096]);       \
  }

  // ---- fragment read addressing (32x32x16 lane maps) ----
  // A region h holds wave-strip local rows {h*64..h*64+63} as region-rows
  // wm*64+..; m-block mb -> region h=mb>>1, region-row wm*64+(mb&1)*32+l31.
  // B region nb holds the wave's col sub-block nb*32 at region-row wn*32+l31.
  // Chunk swizzle: logical chunk c stored at c^(row&7); row&7 == lane&7.
  const int kg32 = lane >> 5;  // k-group 0..1 (8 contiguous K each)
  const int x7 = lane & 7;
  int swz[4];
#pragma unroll
  for (int ks = 0; ks < 4; ++ks) swz[ks] = (((ks * 2 + kg32) ^ x7) << 4);
  const int rA32 = (wm * 64 + l31) * 128;  // byte base (A), +mbi*4096 for mb&1
  const int rB32 = (wn * 32 + l31) * 128;  // byte base (B)

  f32x16 acc[4][2] = {};   // [mb][nb] 32x32 tiles
  bf16x8 aF[2][4], b0F[4], b1F[4];  // aF[mbi][ks]; bNF[ks]

#define RD_A(BUF, H)                                                   \
  {                                                                    \
    const char* p_ = (const char*)&L[BUF][0][H][0] + rA32;             \
    _Pragma("unroll") for (int mbi = 0; mbi < 2; ++mbi)                \
        _Pragma("unroll") for (int ks = 0; ks < 4; ++ks)               \
            aF[mbi][ks] = *(const bf16x8*)(p_ + mbi * 4096 + swz[ks]); \
  }
#define RD_B(BUF, NB, DST)                                             \
  {                                                                    \
    const char* p_ = (const char*)&L[BUF][1][NB][0] + rB32;            \
    _Pragma("unroll") for (int ks = 0; ks < 4; ++ks)                   \
        DST[ks] = *(const bf16x8*)(p_ + swz[ks]);                      \
  }
  // 8 MFMAs: aF x BSET -> acc[MO..MO+1][NC]
#define CLUSTER(BSET, MO, NC)                                               \
  __builtin_amdgcn_s_setprio(1);                                            \
  _Pragma("unroll") for (int mbi = 0; mbi < 2; ++mbi)                       \
      _Pragma("unroll") for (int ks = 0; ks < 4; ++ks)                      \
          acc[MO + mbi][NC] = __builtin_amdgcn_mfma_f32_32x32x16_bf16(      \
              aF[mbi][ks], BSET[ks], acc[MO + mbi][NC], 0, 0, 0);           \
  __builtin_amdgcn_s_setprio(0);

  // ---- prologue: 6 stages in steady FIFO order, retire tile-0 A0,B0 ----
  STAGE(0, 0, 0, 0);  // A0(0)
  STAGE(0, 1, 0, 0);  // B0(0)
  STAGE(0, 0, 1, 0);  // A1(0)
  STAGE(0, 1, 1, 0);  // B1(0)
  STAGE(1, 0, 0, 1);  // A0(1)
  STAGE(1, 1, 0, 1);  // B0(1)
  WAITVM(8);          // A0(0),B0(0) landed; 8 instr in flight
  SBAR();

  for (int t2 = 0; t2 < nt; t2 += 2) {
    const int tn2 = (t2 + 2 < nt) ? t2 + 2 : nt - 1;  // clamped lookahead
    const int tn3 = (t2 + 3 < nt) ? t2 + 3 : nt - 1;
    // ---- ph1: A0xB0 (buf0); reads A0+B0 [12]; stage A1(t2+1)->buf1 ----
    RD_A(0, 0); RD_B(0, 0, b0F);
    STAGE(1, 0, 1, t2 + 1);
    WAITLGK(8);
    SBAR(); WAITLGK(0);
    CLUSTER(b0F, 0, 0);
    WAITVM(6);  // retire A1(t2),B1(t2): ph2/ph3 read them
    SBAR();
    // ---- ph2: A0xB1; reads B1 [4]; stage B1(t2+1)->buf1 ----
    RD_B(0, 1, b1F);
    STAGE(1, 1, 1, t2 + 1);
    SBAR(); WAITLGK(0);
    CLUSTER(b1F, 0, 1);
    SBAR();
    // ---- ph3: A1xB0; reads A1 [8]; stage A0(t2+2)->buf0 ----
    RD_A(0, 1);
    STAGE(0, 0, 0, tn2);
    SBAR(); WAITLGK(0);
    CLUSTER(b0F, 2, 0);
    SBAR();
    // ---- ph4: A1xB1; stage B0(t2+2)->buf0 ----
    STAGE(0, 1, 0, tn2);
    SBAR();
    CLUSTER(b1F, 2, 1);
    WAITVM(8);  // retire A0(t2+1),B0(t2+1): ph5 reads them
    SBAR();
    // ---- ph5: A0xB0 (buf1); reads A0+B0; stage A1(t2+2)->buf0 ----
    RD_A(1, 0); RD_B(1, 0, b0F);
    STAGE(0, 0, 1, tn2);
    WAITLGK(8);
    SBAR(); WAITLGK(0);
    CLUSTER(b0F, 0, 0);
    WAITVM(6);  // retire A1(t2+1),B1(t2+1): ph6/ph7 read them
    SBAR();
    // ---- ph6: A0xB1; reads B1; stage B1(t2+2)->buf0 ----
    RD_B(1, 1, b1F);
    STAGE(0, 1, 1, tn2);
    SBAR(); WAITLGK(0);
    CLUSTER(b1F, 0, 1);
    SBAR();
    // ---- ph7: A1xB0; reads A1; stage A0(t2+3)->buf1 ----
    RD_A(1, 1);
    STAGE(1, 0, 0, tn3);
    SBAR(); WAITLGK(0);
    CLUSTER(b0F, 2, 0);
    SBAR();
    // ---- ph8: A1xB1; stage B0(t2+3)->buf1 ----
    STAGE(1, 1, 0, tn3);
    SBAR();
    CLUSTER(b1F, 2, 1);
    WAITVM(8);  // retire A0(t2+2),B0(t2+2): next ph1 reads them
    SBAR();
  }
  WAITVM(0);  // drain straggler stages

  // ---- epilogue: 32x32 C/D layout (m74/m101): col = lane&31,
  //      row = (reg&3) + 8*(reg>>2) + 4*(lane>>5) ----
  const int colb = bn * 256 + wn * 64 + l31;
  const int rowb = bm * 256 + wm * 128 + 4 * kg32;
  float bv[2];
#pragma unroll
  for (int nb = 0; nb < 2; ++nb) bv[nb] = bias[colb + nb * 32];
#pragma unroll
  for (int mb = 0; mb < 4; ++mb) {
#pragma unroll
    for (int reg = 0; reg < 16; ++reg) {
      const size_t row = (size_t)(rowb + mb * 32 + (reg & 3) + 8 * (reg >> 2));
#pragma unroll
      for (int nb = 0; nb < 2; ++nb) {
        const size_t idx = row * N + colb + nb * 32;
        float v = acc[mb][nb][reg] + bv[nb];
        if (EPI == 0) {
          ((float*)out)[idx] = v + xres[idx];
        } else {
          float ge = 0.5f * v * (1.0f + erff(v * 0.7071067811865475f));
          ((unsigned short*)out)[idx] = f2bf(ge);
        }
      }
    }
  }
#undef RD_A
#undef RD_B
#undef CLUSTER
#undef STAGE
}

// ---------------------------------------------------------------------------
// Row LayerNorm over E=2048: one block per row, 8 elems/thread.
// ---------------------------------------------------------------------------
template <int OUT_BF16>
__global__ __launch_bounds__(256) void ln_row(const float* __restrict__ tin,
                                              const float* __restrict__ gw,
                                              const float* __restrict__ bw,
                                              void* __restrict__ outp) {
  const int row = blockIdx.x;
  const int tid = threadIdx.x;
  const size_t base = (size_t)row * 2048 + tid * 8;
  alignas(16) float v[8];
  *(float4*)(v) = *(const float4*)(tin + base);
  *(float4*)(v + 4) = *(const float4*)(tin + base + 4);
  float s = 0.f, q = 0.f;
#pragma unroll
  for (int i = 0; i < 8; ++i) { s += v[i]; q += v[i] * v[i]; }
#pragma unroll
  for (int m = 32; m >= 1; m >>= 1) {
    s += __shfl_xor(s, m);
    q += __shfl_xor(q, m);
  }
  __shared__ float red[8];
  if ((tid & 63) == 0) {
    red[tid >> 6] = s;
    red[4 + (tid >> 6)] = q;
  }
  __syncthreads();
  s = red[0] + red[1] + red[2] + red[3];
  q = red[4] + red[5] + red[6] + red[7];
  const float mean = s * (1.0f / 2048.0f);
  float var = q * (1.0f / 2048.0f) - mean * mean;
  var = fmaxf(var, 0.0f);
  const float rstd = rsqrtf(var + 1e-5f);
  alignas(16) float gv[8], bv[8];
  *(float4*)(gv) = *(const float4*)(gw + (size_t)tid * 8);
  *(float4*)(gv + 4) = *(const float4*)(gw + (size_t)tid * 8 + 4);
  *(float4*)(bv) = *(const float4*)(bw + (size_t)tid * 8);
  *(float4*)(bv + 4) = *(const float4*)(bw + (size_t)tid * 8 + 4);
  if (OUT_BF16) {
    ushort8 o;
#pragma unroll
    for (int i = 0; i < 8; ++i)
      o[i] = f2bf((v[i] - mean) * rstd * gv[i] + bv[i]);
    *(ushort8*)((unsigned short*)outp + base) = o;
  } else {
    alignas(16) float r[8];
#pragma unroll
    for (int i = 0; i < 8; ++i) r[i] = (v[i] - mean) * rstd * gv[i] + bv[i];
    *(float4*)((float*)outp + base) = *(float4*)(r);
    *(float4*)((float*)outp + base + 4) = *(float4*)(r + 4);
  }
}

// ---------------------------------------------------------------------------
// Launcher — workspace-size-adaptive (R2+ evidence: full path taken).
// ---------------------------------------------------------------------------
extern "C" void kernel_launch(void* const* d_in, const int* in_sizes, int n_in,
                              void* d_out, int out_size, void* d_ws,
                              size_t ws_size, hipStream_t stream) {
  constexpr int M = 8192;  // B*S
  constexpr int E = 2048;
  constexpr int F = 8192;  // 4*E
  const size_t MiB = 1ull << 20;

  const float* x = (const float*)d_in[0];
  // d_in[1] mask, d_in[2] w_attn, d_in[3] b_attn: dead (softmax over size-1)
  const float* w_kv = (const float*)d_in[4];
  const float* b_kv = (const float*)d_in[5];
  const float* ln1_g = (const float*)d_in[6];
  const float* ln1_b = (const float*)d_in[7];
  const float* w_fc = (const float*)d_in[8];
  const float* b_fc = (const float*)d_in[9];
  const float* w_mproj = (const float*)d_in[10];
  const float* b_mproj = (const float*)d_in[11];
  const float* ln2_g = (const float*)d_in[12];
  const float* ln2_b = (const float*)d_in[13];
  float* out = (float*)d_out;
  char* ws = (char*)d_ws;

  float* tbuf = out;  // t1/t2 live in d_out; in-place LN is safe

  int nch;
  unsigned short *xb, *wkvT, *wfcT, *wmpT, *hb, *gch;
  if (ws_size >= 224 * MiB) {
    nch = 1;
    gch = (unsigned short*)(ws + 0);  // 128Mi; aliases xb+wkvT (dead by then)
    xb = (unsigned short*)(ws + 0);
    wkvT = (unsigned short*)(ws + 32 * MiB);
    wfcT = (unsigned short*)(ws + 128 * MiB);
    wmpT = (unsigned short*)(ws + 160 * MiB);
    hb = (unsigned short*)(ws + 192 * MiB);
  } else if (ws_size >= 160 * MiB) {
    nch = 2;
    gch = (unsigned short*)(ws + 0);
    xb = (unsigned short*)(ws + 0);
    wkvT = (unsigned short*)(ws + 32 * MiB);
    hb = (unsigned short*)(ws + 64 * MiB);
    wfcT = (unsigned short*)(ws + 96 * MiB);
    wmpT = (unsigned short*)(ws + 128 * MiB);
  } else {
    nch = 4;
    gch = (unsigned short*)(ws + 0);
    xb = (unsigned short*)(ws + 0);
    wkvT = (unsigned short*)(ws + 32 * MiB);
    hb = (unsigned short*)(ws + 32 * MiB);
    wfcT = (unsigned short*)(ws + 64 * MiB);
    wmpT = (unsigned short*)(ws + 96 * MiB);
  }

  cvt_bf16_kernel<<<(M * E / 8 + 255) / 256, 256, 0, stream>>>(x, xb, M * E / 8);
  transpose_cvt<<<dim3(E / 64, E / 64), 256, 0, stream>>>(w_kv, wkvT, E, E);
  transpose_cvt<<<dim3(F / 64, E / 64), 256, 0, stream>>>(w_fc, wfcT, E, F);
  transpose_cvt<<<dim3(E / 64, F / 64), 256, 0, stream>>>(w_mproj, wmpT, F, E);

  // t1 = x @ w_kv + b_kv + x
  gemm256<0><<<(M / 256) * (E / 256), 512, 0, stream>>>(xb, wkvT, b_kv, x,
                                                        tbuf, E, E);
  // h = LN1(t1) -> bf16
  ln_row<1><<<M, 256, 0, stream>>>(tbuf, ln1_g, ln1_b, hb);
  // g = gelu(h @ w_fc + b_fc); t2 = x + g @ w_mproj + b_mproj  (M-chunked)
  const int Mc = M / nch;
  for (int c = 0; c < nch; ++c) {
    const size_t roff = (size_t)c * Mc;
    gemm256<1><<<(Mc / 256) * (F / 256), 512, 0, stream>>>(
        hb + roff * E, wfcT, b_fc, nullptr, gch, F, E);
    gemm256<0><<<(Mc / 256) * (E / 256), 512, 0, stream>>>(
        gch, wmpT, b_mproj, x + roff * E, tbuf + roff * E, E, F);
  }
  // out = LN2(t2) in place
  ln_row<0><<<M, 256, 0, stream>>>(tbuf, ln2_g, ln2_b, out);
}